// Round 10
// baseline (258.525 us; speedup 1.0000x reference)
//
#include <hip/hip_runtime.h>
#include <hip/hip_cooperative_groups.h>

namespace cg = cooperative_groups;

#define N_NODES 100000
#define N_EDGES 1600000
#define EMBED_DIM 64

#define RPB 256                                   // rows per bucket
#define NBKT ((N_NODES + RPB - 1) / RPB)          // 391
#define CAP 4608                                  // slots per bucket (mean 4092, +8 sigma)
#define TILE 4096                                 // edges per tile (= per block, phase A)
#define NTILE ((N_EDGES + TILE - 1) / TILE)       // 391  (== NBKT, one block does both roles)
#define OVCAP 8192                                // overflow backstop
#define EPT 5                                     // ceil(CAP/1024) edges/thread in phase B

// ---- fused-kernel LDS layout (byte offsets; union of phase A and phase B) ----
// phase A header: hist/off/cur/gbase[NBKT] + wsum[16] + stotal = 1581 ints = 6324 B
#define SM_A_STAGE 6336                           // int2 stage[TILE]  (32768 B)
#define SM_A_DG    (SM_A_STAGE + TILE * 8)        // int  dg[TILE]     (16384 B)
#define SM_BYTES   (SM_A_DG + TILE * 4)           // 55488 B -> 2 blocks/CU
// phase B header: h/ofs/cur[RPB] + wsum[16] = 784 ints = 3136 B
#define SM_B_STAGE 3200                           // int2 stage[CAP]   (36864 B; ends 40064)

// ============================================================================
// Fused cooperative kernel: zero -> sync -> binA(staged) -> sync -> binB+gather
// Replaces 4 dispatches (memset, binA, k_bg, overflow) with 1: r9 analysis
// showed >=41us of inter-dispatch overhead (~10us each).
// 391 blocks x 1024 thr, 55.5KB LDS, launch_bounds(1024,8) -> VGPR<=64 ->
// 2 blocks/CU co-resident (512 slots >= 391, cooperative launch valid).
// ============================================================================
__global__ __launch_bounds__(1024, 8) void k_fused(const int* __restrict__ rows,
                                                   const int* __restrict__ cols,
                                                   const float* __restrict__ vals,
                                                   int* __restrict__ gcur,
                                                   int2* __restrict__ packed,
                                                   int* __restrict__ ov_cnt,
                                                   int4* __restrict__ ov,
                                                   const float* __restrict__ x,
                                                   float* __restrict__ out) {
    __shared__ __align__(16) char smem[SM_BYTES];
    cg::grid_group grid = cg::this_grid();
    const int tid = threadIdx.x;
    const int lane = tid & 63;
    const int wid = tid >> 6;          // 0..15
    const int blk = blockIdx.x;        // tile id (phase A) == bucket id (phase B)

    // ---------------- phase 0: zero gcur[NBKT] + ov_cnt (adjacent) ----------------
    {
        int gtid = blk * 1024 + tid;
        if (gtid < NBKT + 1) gcur[gtid] = 0;
    }
    grid.sync();

    // ---------------- phase A: tile counting-sort, staged flush (r5-verified) ----
    {
        int* hist  = (int*)smem;
        int* off   = hist + NBKT;
        int* cur   = off + NBKT;
        int* gbase = cur + NBKT;
        int* wsum  = gbase + NBKT;     // 16
        int* stot  = wsum + 16;
        int2* stage = (int2*)(smem + SM_A_STAGE);
        int*  dg    = (int*)(smem + SM_A_DG);

        for (int i = tid; i < NBKT; i += 1024) hist[i] = 0;
        __syncthreads();

        // pass 1: histogram; rows cached in registers (int4 vector load)
        const int e0 = blk * TILE;
        const int eb = e0 + 4 * tid;
        int rr0 = -1, rr1 = -1, rr2 = -1, rr3 = -1;
        if (eb + 3 < N_EDGES) {
            int4 r4 = *(const int4*)(rows + eb);
            rr0 = r4.x; rr1 = r4.y; rr2 = r4.z; rr3 = r4.w;
        } else {
            if (eb + 0 < N_EDGES) rr0 = rows[eb + 0];
            if (eb + 1 < N_EDGES) rr1 = rows[eb + 1];
            if (eb + 2 < N_EDGES) rr2 = rows[eb + 2];
            if (eb + 3 < N_EDGES) rr3 = rows[eb + 3];
        }
        if (rr0 >= 0) atomicAdd(&hist[rr0 >> 8], 1);
        if (rr1 >= 0) atomicAdd(&hist[rr1 >> 8], 1);
        if (rr2 >= 0) atomicAdd(&hist[rr2 >> 8], 1);
        if (rr3 >= 0) atomicAdd(&hist[rr3 >> 8], 1);
        __syncthreads();

        // exclusive scan hist[0..NBKT): wave shfl scan + 16-partial combine
        int v = (tid < NBKT) ? hist[tid] : 0;
        int incl = v;
        for (int o = 1; o < 64; o <<= 1) {
            int t = __shfl_up(incl, o, 64);
            if (lane >= o) incl += t;
        }
        if (lane == 63) wsum[wid] = incl;
        __syncthreads();
        if (wid == 0 && lane < 16) {
            int s = wsum[lane];
            int si = s;
            for (int o = 1; o < 16; o <<= 1) {
                int t = __shfl_up(si, o, 64);
                if (lane >= o) si += t;
            }
            wsum[lane] = si - s;       // exclusive wave offset
            if (lane == 15) *stot = si;
        }
        __syncthreads();
        int excl = incl - v + wsum[wid];
        if (tid < NBKT) { off[tid] = excl; cur[tid] = excl; }

        // bulk global reservation
        for (int b = tid; b < NBKT; b += 1024) {
            int c = hist[b];
            gbase[b] = c ? atomicAdd(&gcur[b], c) : 0;
        }
        __syncthreads();

        // pass 2: grouped placement into LDS staging (cols/vals via int4/float4)
        int cc0 = 0, cc1 = 0, cc2 = 0, cc3 = 0;
        float vv0 = 0.f, vv1 = 0.f, vv2 = 0.f, vv3 = 0.f;
        if (eb + 3 < N_EDGES) {
            int4 c4 = *(const int4*)(cols + eb);
            float4 v4 = *(const float4*)(vals + eb);
            cc0 = c4.x; cc1 = c4.y; cc2 = c4.z; cc3 = c4.w;
            vv0 = v4.x; vv1 = v4.y; vv2 = v4.z; vv3 = v4.w;
        } else {
            if (eb + 0 < N_EDGES) { cc0 = cols[eb + 0]; vv0 = vals[eb + 0]; }
            if (eb + 1 < N_EDGES) { cc1 = cols[eb + 1]; vv1 = vals[eb + 1]; }
            if (eb + 2 < N_EDGES) { cc2 = cols[eb + 2]; vv2 = vals[eb + 2]; }
            if (eb + 3 < N_EDGES) { cc3 = cols[eb + 3]; vv3 = vals[eb + 3]; }
        }
#define PLACE(RR, CC, VV)                                                     \
        if (RR >= 0) {                                                        \
            int b_ = RR >> 8;                                                 \
            int p_ = atomicAdd(&cur[b_], 1);                                  \
            stage[p_] = make_int2(((RR & (RPB - 1)) << 17) | CC,              \
                                  __float_as_int(VV));                        \
            int d_ = gbase[b_] + (p_ - off[b_]);                              \
            dg[p_] = (d_ < CAP) ? (b_ * CAP + d_) : (0x40000000 | b_);        \
        }
        PLACE(rr0, cc0, vv0)
        PLACE(rr1, cc1, vv1)
        PLACE(rr2, cc2, vv2)
        PLACE(rr3, cc3, vv3)
#undef PLACE
        __syncthreads();

        // flush: consecutive staged elements -> consecutive global slots
        int total = *stot;
        for (int j = tid; j < total; j += 1024) {
            int d = dg[j];
            int2 ev = stage[j];
            if (d & 0x40000000) {      // overflow backstop (statistically never)
                int b_ = d & 0xFFFF;
                int ovi = atomicAdd(ov_cnt, 1);
                if (ovi < OVCAP) {
                    int r = b_ * RPB + (((unsigned)ev.x) >> 17);
                    ov[ovi] = make_int4(r, ev.x & 0x1FFFF, ev.y, 0);
                }
            } else {
                packed[d] = ev;
            }
        }
    }
    grid.sync();

    // ---------------- phase B: per-bucket row-sort + gather (r8-verified) --------
    {
        int* h    = (int*)smem;
        int* ofs  = h + RPB;
        int* cur  = ofs + RPB;
        int* wsum = cur + RPB;         // 16
        int2* stage = (int2*)(smem + SM_B_STAGE);
        const int b = blk;
        int n = gcur[b];
        if (n > CAP) n = CAP;
        const int base = b * CAP;

        if (tid < RPB) h[tid] = 0;
        __syncthreads();

        // load edges into registers + histogram rows
        int2 ereg[EPT];
        int lr[EPT];
#pragma unroll
        for (int jj = 0; jj < EPT; ++jj) {
            int j = tid + jj * 1024;
            lr[jj] = -1;
            if (j < n) {
                int2 e = packed[base + j];
                ereg[jj] = e;
                int r = ((unsigned)e.x) >> 17;
                lr[jj] = r;
                atomicAdd(&h[r], 1);
            }
        }
        __syncthreads();

        // exclusive scan h[0..255] (waves 0..3)
        int hv = (tid < RPB) ? h[tid] : 0;
        int incl = hv;
        for (int o = 1; o < 64; o <<= 1) {
            int t = __shfl_up(incl, o, 64);
            if (lane >= o) incl += t;
        }
        if (tid < RPB && lane == 63) wsum[wid] = incl;
        __syncthreads();
        if (wid == 0 && lane < 4) {
            int s = wsum[lane];
            int si = s;
            for (int o = 1; o < 4; o <<= 1) {
                int t = __shfl_up(si, o, 64);
                if (lane >= o) si += t;
            }
            wsum[lane] = si - s;
        }
        __syncthreads();
        if (tid < RPB) {
            int o2 = incl - hv + wsum[wid];
            ofs[tid] = o2;
            cur[tid] = o2;
        }
        __syncthreads();

        // place row-sorted into LDS (source = registers -> no RAW hazard)
#pragma unroll
        for (int jj = 0; jj < EPT; ++jj) {
            if (lr[jj] >= 0) {
                int p = atomicAdd(&cur[lr[jj]], 1);
                stage[p] = ereg[jj];
            }
        }
        __syncthreads();

        // gather: wave wid handles rows wid*16 .. wid*16+15
        const int half = lane >> 5;    // 0: even edges, 1: odd edges
        const int hl = lane & 31;      // dim-pair index
        const float2* __restrict__ x2 = (const float2*)x;
        for (int i = 0; i < 16; ++i) {
            int r = wid * 16 + i;
            int grow = b * RPB + r;
            if (grow >= N_NODES) break;
            int deg = h[r];
            int beg = ofs[r];
            float ax = 0.f, ay = 0.f;
            for (int j0 = 0; j0 < deg; j0 += 16) {
                float pv[8];
                float2 xv[8];
#pragma unroll
                for (int k = 0; k < 8; ++k) {
                    int j = j0 + 2 * k + half;
                    int2 e = (j < deg) ? stage[beg + j] : make_int2(0, 0);
                    pv[k] = __int_as_float(e.y);           // 0 for pad
                    xv[k] = x2[(e.x & 0x1FFFF) * 32 + hl]; // x[0] row for pad
                }
#pragma unroll
                for (int k = 0; k < 8; ++k) {
                    ax += pv[k] * xv[k].x;
                    ay += pv[k] * xv[k].y;
                }
            }
            ax += __shfl_xor(ax, 32);
            ay += __shfl_xor(ay, 32);
            if (half == 0) {
                ((float2*)out)[(size_t)grow * 32 + hl] = make_float2(ax, ay);
            }
        }

        // inline overflow cleanup for this bucket's rows (expected n==0)
        int nov = *ov_cnt;
        if (nov > OVCAP) nov = OVCAP;
        for (int i = wid; i < nov; i += 16) {
            int4 e = ov[i];
            if ((e.x >> 8) == b) {
                atomicAdd(&out[(size_t)e.x * EMBED_DIM + lane],
                          __int_as_float(e.z) * x[(size_t)e.y * EMBED_DIM + lane]);
            }
        }
    }
}

// ============================================================================
// Fallback path (cooperative launch unavailable): verified r8 pipeline
// ============================================================================
__global__ __launch_bounds__(512) void k_binA(const int* __restrict__ rows,
                                              const int* __restrict__ cols,
                                              const float* __restrict__ vals,
                                              int* __restrict__ gcur,
                                              int2* __restrict__ packed,
                                              int* __restrict__ ov_cnt,
                                              int4* __restrict__ ov) {
    __shared__ int hist[NBKT];
    __shared__ int off[NBKT];
    __shared__ int cur[NBKT];
    __shared__ int gbase[NBKT];
    __shared__ int wsum[8];
    __shared__ int stotal;
    __shared__ int2 stage[TILE];
    __shared__ int dg[TILE];
    const int tid = threadIdx.x;
    const int lane = tid & 63;
    const int wid = tid >> 6;
    const int e0 = blockIdx.x * TILE;

    for (int i = tid; i < NBKT; i += 512) hist[i] = 0;
    __syncthreads();
    for (int i = tid; i < TILE; i += 512) {
        int e = e0 + i;
        if (e < N_EDGES) atomicAdd(&hist[rows[e] >> 8], 1);
    }
    __syncthreads();
    int v = (tid < NBKT) ? hist[tid] : 0;
    int incl = v;
    for (int o = 1; o < 64; o <<= 1) {
        int t = __shfl_up(incl, o, 64);
        if (lane >= o) incl += t;
    }
    if (lane == 63) wsum[wid] = incl;
    __syncthreads();
    if (wid == 0 && lane < 8) {
        int s = wsum[lane];
        int si = s;
        for (int o = 1; o < 8; o <<= 1) {
            int t = __shfl_up(si, o, 64);
            if (lane >= o) si += t;
        }
        wsum[lane] = si - s;
        if (lane == 7) stotal = si;
    }
    __syncthreads();
    int excl = incl - v + wsum[wid];
    if (tid < NBKT) { off[tid] = excl; cur[tid] = excl; }
    for (int b = tid; b < NBKT; b += 512) {
        int c = hist[b];
        gbase[b] = c ? atomicAdd(&gcur[b], c) : 0;
    }
    __syncthreads();
    for (int i = tid; i < TILE; i += 512) {
        int e = e0 + i;
        if (e < N_EDGES) {
            int r = rows[e];
            int b = r >> 8;
            int p = atomicAdd(&cur[b], 1);
            stage[p] = make_int2(((r & (RPB - 1)) << 17) | cols[e],
                                 __float_as_int(vals[e]));
            int d = gbase[b] + (p - off[b]);
            dg[p] = (d < CAP) ? (b * CAP + d) : (0x40000000 | b);
        }
    }
    __syncthreads();
    int total = stotal;
    for (int j = tid; j < total; j += 512) {
        int d = dg[j];
        int2 ev = stage[j];
        if (d & 0x40000000) {
            int b = d & 0xFFFF;
            int ovi = atomicAdd(ov_cnt, 1);
            if (ovi < OVCAP) {
                int r = b * RPB + (((unsigned)ev.x) >> 17);
                ov[ovi] = make_int4(r, ev.x & 0x1FFFF, ev.y, 0);
            }
        } else {
            packed[d] = ev;
        }
    }
}

__global__ __launch_bounds__(1024) void k_bg(const float* __restrict__ x,
                                             const int* __restrict__ gcur,
                                             const int2* __restrict__ packed,
                                             float* __restrict__ out) {
    __shared__ int2 stage[CAP];
    __shared__ int h[RPB];
    __shared__ int ofs[RPB];
    __shared__ int cur[RPB];
    __shared__ int wsum[4];
    const int b = blockIdx.x;
    const int tid = threadIdx.x;
    const int lane = tid & 63;
    const int wid = tid >> 6;
    int n = gcur[b];
    if (n > CAP) n = CAP;
    const int base = b * CAP;

    if (tid < RPB) h[tid] = 0;
    __syncthreads();
    int2 ereg[EPT];
    int lr[EPT];
#pragma unroll
    for (int jj = 0; jj < EPT; ++jj) {
        int j = tid + jj * 1024;
        lr[jj] = -1;
        if (j < n) {
            int2 e = packed[base + j];
            ereg[jj] = e;
            int r = ((unsigned)e.x) >> 17;
            lr[jj] = r;
            atomicAdd(&h[r], 1);
        }
    }
    __syncthreads();
    int hv = (tid < RPB) ? h[tid] : 0;
    int incl = hv;
    for (int o = 1; o < 64; o <<= 1) {
        int t = __shfl_up(incl, o, 64);
        if (lane >= o) incl += t;
    }
    if (tid < RPB && lane == 63) wsum[wid] = incl;
    __syncthreads();
    if (wid == 0 && lane < 4) {
        int s = wsum[lane];
        int si = s;
        for (int o = 1; o < 4; o <<= 1) {
            int t = __shfl_up(si, o, 64);
            if (lane >= o) si += t;
        }
        wsum[lane] = si - s;
    }
    __syncthreads();
    if (tid < RPB) {
        int o2 = incl - hv + wsum[wid];
        ofs[tid] = o2;
        cur[tid] = o2;
    }
    __syncthreads();
#pragma unroll
    for (int jj = 0; jj < EPT; ++jj) {
        if (lr[jj] >= 0) {
            int p = atomicAdd(&cur[lr[jj]], 1);
            stage[p] = ereg[jj];
        }
    }
    __syncthreads();
    const int half = lane >> 5;
    const int hl = lane & 31;
    const float2* __restrict__ x2 = (const float2*)x;
    for (int i = 0; i < 16; ++i) {
        int r = wid * 16 + i;
        int grow = b * RPB + r;
        if (grow >= N_NODES) break;
        int deg = h[r];
        int beg = ofs[r];
        float ax = 0.f, ay = 0.f;
        for (int j0 = 0; j0 < deg; j0 += 16) {
            float pv[8];
            float2 xv[8];
#pragma unroll
            for (int k = 0; k < 8; ++k) {
                int j = j0 + 2 * k + half;
                int2 e = (j < deg) ? stage[beg + j] : make_int2(0, 0);
                pv[k] = __int_as_float(e.y);
                xv[k] = x2[(e.x & 0x1FFFF) * 32 + hl];
            }
#pragma unroll
            for (int k = 0; k < 8; ++k) {
                ax += pv[k] * xv[k].x;
                ay += pv[k] * xv[k].y;
            }
        }
        ax += __shfl_xor(ax, 32);
        ay += __shfl_xor(ay, 32);
        if (half == 0) {
            ((float2*)out)[(size_t)grow * 32 + hl] = make_float2(ax, ay);
        }
    }
}

__global__ __launch_bounds__(256) void k_overflow(const float* __restrict__ x,
                                                  const int* __restrict__ ov_cnt,
                                                  const int4* __restrict__ ov,
                                                  float* __restrict__ out) {
    int n = *ov_cnt;
    if (n > OVCAP) n = OVCAP;
    int lane = threadIdx.x & 63;
    int wglobal = (blockIdx.x * 256 + threadIdx.x) >> 6;
    for (int i = wglobal; i < n; i += 64 * 4) {
        int4 e = ov[i];
        atomicAdd(&out[e.x * EMBED_DIM + lane],
                  __int_as_float(e.z) * x[e.y * EMBED_DIM + lane]);
    }
}

__global__ __launch_bounds__(256) void spmm_scatter_kernel(
    const float* __restrict__ x, const float* __restrict__ vals,
    const int* __restrict__ rows, const int* __restrict__ cols,
    float* __restrict__ out) {
    const int wave_in_block = threadIdx.x >> 6;
    const int lane = threadIdx.x & 63;
    const int e = blockIdx.x * 4 + wave_in_block;
    if (e >= N_EDGES) return;
    const float m = vals[e] * x[cols[e] * EMBED_DIM + lane];
    atomicAdd(&out[rows[e] * EMBED_DIM + lane], m);
}

extern "C" void kernel_launch(void* const* d_in, const int* in_sizes, int n_in,
                              void* d_out, int out_size, void* d_ws, size_t ws_size,
                              hipStream_t stream) {
    const int*   rows = (const int*)d_in[2];
    const int*   cols = (const int*)d_in[3];
    const float* vals = (const float*)d_in[1];
    const float* x    = (const float*)d_in[0];
    float* out = (float*)d_out;

    // ws layout: packed[NBKT*CAP] int2 | ov[OVCAP] int4 | gcur[NBKT] | ov_cnt
    const size_t packed_b = (size_t)NBKT * CAP * 8;         // 14,413,824 (16B-aligned)
    const size_t ov_b     = (size_t)OVCAP * 16;
    const size_t need = packed_b + ov_b + ((size_t)NBKT + 1) * 4;
    if (ws_size < need) {
        hipMemsetAsync(out, 0, (size_t)out_size * sizeof(float), stream);
        spmm_scatter_kernel<<<(N_EDGES + 3) / 4, 256, 0, stream>>>(x, vals, rows, cols, out);
        return;
    }

    int2* packed  = (int2*)d_ws;
    int4* ov      = (int4*)((char*)d_ws + packed_b);
    int*  gcur    = (int*)((char*)d_ws + packed_b + ov_b);
    int*  ov_cnt  = gcur + NBKT;

    // ---- tier 1: single fused cooperative kernel (zeroing done in-kernel) ----
    void* args[] = { (void*)&rows, (void*)&cols, (void*)&vals, (void*)&gcur,
                     (void*)&packed, (void*)&ov_cnt, (void*)&ov, (void*)&x,
                     (void*)&out };
    hipError_t err = hipLaunchCooperativeKernel((const void*)k_fused,
                                                dim3(NBKT), dim3(1024),
                                                args, 0, stream);
    if (err == hipSuccess) return;

    // ---- tier 2: verified r8 pipeline ----
    hipMemsetAsync(gcur, 0, ((size_t)NBKT + 1) * sizeof(int), stream);
    k_binA<<<NTILE, 512, 0, stream>>>(rows, cols, vals, gcur, packed, ov_cnt, ov);
    k_bg<<<NBKT, 1024, 0, stream>>>(x, gcur, (const int2*)packed, out);
    k_overflow<<<64, 256, 0, stream>>>(x, ov_cnt, ov, out);
}

// Round 11
// 167.017 us; speedup vs baseline: 1.5479x; 1.5479x over previous
//
#include <hip/hip_runtime.h>

#define N_NODES 100000
#define N_EDGES 1600000
#define EMBED_DIM 64

#define RPB 256                                   // rows per bucket
#define NBKT ((N_NODES + RPB - 1) / RPB)          // 391
#define CAP 4608                                  // slots per bucket (mean 4092, +8 sigma)
#define TILE 4096                                 // edges per binA block
#define NTILE ((N_EDGES + TILE - 1) / TILE)       // 391
#define OVCAP 8192                                // overflow backstop
#define EPT 5                                     // ceil(CAP/1024) edges/thread in k_bg

// ---------- pass A: tile counting-sort into bucket regions (staged flush) ----------
// 1024 threads, 4 edges/thread, int4/float4 vector loads (validated inside r10's
// fused kernel). Staged LDS flush retained: r6/r9 proved direct scattered global
// placement pays partial-line write amplification (r6: 100MB WRITE, r9: +13us).
__global__ __launch_bounds__(1024) void k_binA(const int* __restrict__ rows,
                                               const int* __restrict__ cols,
                                               const float* __restrict__ vals,
                                               int* __restrict__ gcur,
                                               int2* __restrict__ packed,
                                               int* __restrict__ ov_cnt,
                                               int4* __restrict__ ov) {
    __shared__ int hist[NBKT];
    __shared__ int off[NBKT];
    __shared__ int cur[NBKT];
    __shared__ int gbase[NBKT];
    __shared__ int wsum[16];
    __shared__ int stotal;
    __shared__ int2 stage[TILE];   // 32 KB
    __shared__ int dg[TILE];       // 16 KB   -> total ~55.5 KB, 2 blocks/CU
    const int tid = threadIdx.x;
    const int lane = tid & 63;
    const int wid = tid >> 6;      // 0..15
    const int e0 = blockIdx.x * TILE;

    for (int i = tid; i < NBKT; i += 1024) hist[i] = 0;
    __syncthreads();

    // pass 1: histogram; rows cached in registers (int4 vector load)
    const int eb = e0 + 4 * tid;
    int rr0 = -1, rr1 = -1, rr2 = -1, rr3 = -1;
    if (eb + 3 < N_EDGES) {
        int4 r4 = *(const int4*)(rows + eb);
        rr0 = r4.x; rr1 = r4.y; rr2 = r4.z; rr3 = r4.w;
    } else {
        if (eb + 0 < N_EDGES) rr0 = rows[eb + 0];
        if (eb + 1 < N_EDGES) rr1 = rows[eb + 1];
        if (eb + 2 < N_EDGES) rr2 = rows[eb + 2];
        if (eb + 3 < N_EDGES) rr3 = rows[eb + 3];
    }
    if (rr0 >= 0) atomicAdd(&hist[rr0 >> 8], 1);
    if (rr1 >= 0) atomicAdd(&hist[rr1 >> 8], 1);
    if (rr2 >= 0) atomicAdd(&hist[rr2 >> 8], 1);
    if (rr3 >= 0) atomicAdd(&hist[rr3 >> 8], 1);
    __syncthreads();

    // exclusive scan hist[0..NBKT): wave shfl scan + 16-partial combine
    int v = (tid < NBKT) ? hist[tid] : 0;
    int incl = v;
    for (int o = 1; o < 64; o <<= 1) {
        int t = __shfl_up(incl, o, 64);
        if (lane >= o) incl += t;
    }
    if (lane == 63) wsum[wid] = incl;
    __syncthreads();
    if (wid == 0 && lane < 16) {
        int s = wsum[lane];
        int si = s;
        for (int o = 1; o < 16; o <<= 1) {
            int t = __shfl_up(si, o, 64);
            if (lane >= o) si += t;
        }
        wsum[lane] = si - s;           // exclusive wave offset
        if (lane == 15) stotal = si;   // tile total
    }
    __syncthreads();
    int excl = incl - v + wsum[wid];
    if (tid < NBKT) { off[tid] = excl; cur[tid] = excl; }

    // bulk global reservation: one atomic per non-empty bucket
    for (int b = tid; b < NBKT; b += 1024) {
        int c = hist[b];
        gbase[b] = c ? atomicAdd(&gcur[b], c) : 0;
    }
    __syncthreads();

    // pass 2: grouped placement into LDS staging (cols/vals via int4/float4)
    int cc0 = 0, cc1 = 0, cc2 = 0, cc3 = 0;
    float vv0 = 0.f, vv1 = 0.f, vv2 = 0.f, vv3 = 0.f;
    if (eb + 3 < N_EDGES) {
        int4 c4 = *(const int4*)(cols + eb);
        float4 v4 = *(const float4*)(vals + eb);
        cc0 = c4.x; cc1 = c4.y; cc2 = c4.z; cc3 = c4.w;
        vv0 = v4.x; vv1 = v4.y; vv2 = v4.z; vv3 = v4.w;
    } else {
        if (eb + 0 < N_EDGES) { cc0 = cols[eb + 0]; vv0 = vals[eb + 0]; }
        if (eb + 1 < N_EDGES) { cc1 = cols[eb + 1]; vv1 = vals[eb + 1]; }
        if (eb + 2 < N_EDGES) { cc2 = cols[eb + 2]; vv2 = vals[eb + 2]; }
        if (eb + 3 < N_EDGES) { cc3 = cols[eb + 3]; vv3 = vals[eb + 3]; }
    }
#define PLACE(RR, CC, VV)                                                     \
    if (RR >= 0) {                                                            \
        int b_ = RR >> 8;                                                     \
        int p_ = atomicAdd(&cur[b_], 1);                                      \
        stage[p_] = make_int2(((RR & (RPB - 1)) << 17) | CC,                  \
                              __float_as_int(VV));                            \
        int d_ = gbase[b_] + (p_ - off[b_]);                                  \
        dg[p_] = (d_ < CAP) ? (b_ * CAP + d_) : (0x40000000 | b_);            \
    }
    PLACE(rr0, cc0, vv0)
    PLACE(rr1, cc1, vv1)
    PLACE(rr2, cc2, vv2)
    PLACE(rr3, cc3, vv3)
#undef PLACE
    __syncthreads();

    // flush: consecutive staged elements -> consecutive global slots (dense lines)
    int total = stotal;
    for (int j = tid; j < total; j += 1024) {
        int d = dg[j];
        int2 ev = stage[j];
        if (d & 0x40000000) {          // overflow backstop (statistically never)
            int b_ = d & 0xFFFF;
            int ovi = atomicAdd(ov_cnt, 1);
            if (ovi < OVCAP) {
                int r = b_ * RPB + (((unsigned)ev.x) >> 17);
                ov[ovi] = make_int4(r, ev.x & 0x1FFFF, ev.y, 0);
            }
        } else {
            packed[d] = ev;
        }
    }
}

// ---------- fused binB+gather: one block per bucket (r8-verified) ----------
// + inline per-bucket overflow sweep at the end (kills the k_overflow dispatch).
__global__ __launch_bounds__(1024) void k_bg(const float* __restrict__ x,
                                             const int* __restrict__ gcur,
                                             const int2* __restrict__ packed,
                                             const int* __restrict__ ov_cnt,
                                             const int4* __restrict__ ov,
                                             float* __restrict__ out) {
    __shared__ int2 stage[CAP];    // 36 KB
    __shared__ int h[RPB];
    __shared__ int ofs[RPB];
    __shared__ int cur[RPB];
    __shared__ int wsum[4];
    const int b = blockIdx.x;
    const int tid = threadIdx.x;
    const int lane = tid & 63;
    const int wid = tid >> 6;      // 0..15
    int n = gcur[b];
    if (n > CAP) n = CAP;
    const int base = b * CAP;

    if (tid < RPB) h[tid] = 0;
    __syncthreads();

    // load edges into registers + histogram rows
    int2 ereg[EPT];
    int lr[EPT];
#pragma unroll
    for (int jj = 0; jj < EPT; ++jj) {
        int j = tid + jj * 1024;
        lr[jj] = -1;
        if (j < n) {
            int2 e = packed[base + j];
            ereg[jj] = e;
            int r = ((unsigned)e.x) >> 17;
            lr[jj] = r;
            atomicAdd(&h[r], 1);
        }
    }
    __syncthreads();

    // exclusive scan h[0..255] (waves 0..3)
    int hv = (tid < RPB) ? h[tid] : 0;
    int incl = hv;
    for (int o = 1; o < 64; o <<= 1) {
        int t = __shfl_up(incl, o, 64);
        if (lane >= o) incl += t;
    }
    if (tid < RPB && lane == 63) wsum[wid] = incl;
    __syncthreads();
    if (wid == 0 && lane < 4) {
        int s = wsum[lane];
        int si = s;
        for (int o = 1; o < 4; o <<= 1) {
            int t = __shfl_up(si, o, 64);
            if (lane >= o) si += t;
        }
        wsum[lane] = si - s;
    }
    __syncthreads();
    if (tid < RPB) {
        int o2 = incl - hv + wsum[wid];
        ofs[tid] = o2;
        cur[tid] = o2;
    }
    __syncthreads();

    // place row-sorted into LDS (source = registers -> no RAW hazard)
#pragma unroll
    for (int jj = 0; jj < EPT; ++jj) {
        if (lr[jj] >= 0) {
            int p = atomicAdd(&cur[lr[jj]], 1);
            stage[p] = ereg[jj];
        }
    }
    __syncthreads();

    // gather: wave wid handles rows wid*16 .. wid*16+15
    const int half = lane >> 5;    // 0: even edges, 1: odd edges
    const int hl = lane & 31;      // dim-pair index
    const float2* __restrict__ x2 = (const float2*)x;
    for (int i = 0; i < 16; ++i) {
        int r = wid * 16 + i;
        int grow = b * RPB + r;
        if (grow >= N_NODES) break;
        int deg = h[r];
        int beg = ofs[r];
        float ax = 0.f, ay = 0.f;
        for (int j0 = 0; j0 < deg; j0 += 16) {
            float pv[8];
            float2 xv[8];
#pragma unroll
            for (int k = 0; k < 8; ++k) {
                int j = j0 + 2 * k + half;
                int2 e = (j < deg) ? stage[beg + j] : make_int2(0, 0);
                pv[k] = __int_as_float(e.y);               // 0 for pad
                xv[k] = x2[(e.x & 0x1FFFF) * 32 + hl];     // x[0] row for pad
            }
#pragma unroll
            for (int k = 0; k < 8; ++k) {
                ax += pv[k] * xv[k].x;
                ay += pv[k] * xv[k].y;
            }
        }
        ax += __shfl_xor(ax, 32);
        ay += __shfl_xor(ay, 32);
        if (half == 0) {
            ((float2*)out)[(size_t)grow * 32 + hl] = make_float2(ax, ay);
        }
    }

    // inline overflow cleanup for this bucket's rows (expected nov==0)
    __syncthreads();   // drain gather stores before atomics on same rows
    int nov = *ov_cnt;
    if (nov > OVCAP) nov = OVCAP;
    for (int i = wid; i < nov; i += 16) {
        int4 e = ov[i];
        if ((e.x >> 8) == b) {
            atomicAdd(&out[(size_t)e.x * EMBED_DIM + lane],
                      __int_as_float(e.z) * x[(size_t)e.y * EMBED_DIM + lane]);
        }
    }
}

// ---------- fallback (ws too small): atomic scatter ----------
__global__ __launch_bounds__(256) void spmm_scatter_kernel(
    const float* __restrict__ x, const float* __restrict__ vals,
    const int* __restrict__ rows, const int* __restrict__ cols,
    float* __restrict__ out) {
    const int wave_in_block = threadIdx.x >> 6;
    const int lane = threadIdx.x & 63;
    const int e = blockIdx.x * 4 + wave_in_block;
    if (e >= N_EDGES) return;
    const float m = vals[e] * x[cols[e] * EMBED_DIM + lane];
    atomicAdd(&out[rows[e] * EMBED_DIM + lane], m);
}

extern "C" void kernel_launch(void* const* d_in, const int* in_sizes, int n_in,
                              void* d_out, int out_size, void* d_ws, size_t ws_size,
                              hipStream_t stream) {
    const float* x    = (const float*)d_in[0];
    const float* vals = (const float*)d_in[1];
    const int*   rows = (const int*)d_in[2];
    const int*   cols = (const int*)d_in[3];
    float* out = (float*)d_out;

    // ws layout: packed[NBKT*CAP] int2 | ov[OVCAP] int4 | gcur[NBKT] | ov_cnt
    const size_t packed_b = (size_t)NBKT * CAP * 8;         // 14,413,824 (16B-aligned)
    const size_t ov_b     = (size_t)OVCAP * 16;
    const size_t need = packed_b + ov_b + ((size_t)NBKT + 1) * 4;
    if (ws_size < need) {
        hipMemsetAsync(out, 0, (size_t)out_size * sizeof(float), stream);
        spmm_scatter_kernel<<<(N_EDGES + 3) / 4, 256, 0, stream>>>(x, vals, rows, cols, out);
        return;
    }

    int2* packed  = (int2*)d_ws;
    int4* ov      = (int4*)((char*)d_ws + packed_b);
    int*  gcur    = (int*)((char*)d_ws + packed_b + ov_b);
    int*  ov_cnt  = gcur + NBKT;

    // single memset: gcur[NBKT] + ov_cnt adjacent
    hipMemsetAsync(gcur, 0, ((size_t)NBKT + 1) * sizeof(int), stream);

    k_binA<<<NTILE, 1024, 0, stream>>>(rows, cols, vals, gcur, packed, ov_cnt, ov);
    k_bg<<<NBKT, 1024, 0, stream>>>(x, gcur, (const int2*)packed, ov_cnt, ov, out);
}

// Round 12
// 165.819 us; speedup vs baseline: 1.5591x; 1.0072x over previous
//
#include <hip/hip_runtime.h>

#define N_NODES 100000
#define N_EDGES 1600000
#define EMBED_DIM 64

#define RPB 128                                   // rows per bucket (was 256: r12 halves it for 2x k_bg grid)
#define NBKT ((N_NODES + RPB - 1) / RPB)          // 782
#define CAP 2304                                  // slots per bucket (mean 2048, +5.7 sigma)
#define TILE 4096                                 // edges per binA block
#define NTILE ((N_EDGES + TILE - 1) / TILE)       // 391
#define OVCAP 8192                                // overflow backstop
#define EPT 3                                     // ceil(CAP/1024) edges/thread in k_bg

// ---------- pass A: tile counting-sort into bucket regions (staged flush) ----------
// 1024 threads, 4 edges/thread, int4/float4 vector loads. Staged LDS flush
// retained: r6/r9 proved direct scattered global placement pays partial-line
// write amplification. Header arrays now 782 buckets (~12.5KB); LDS ~61.7KB
// -> 2 blocks/CU.
__global__ __launch_bounds__(1024) void k_binA(const int* __restrict__ rows,
                                               const int* __restrict__ cols,
                                               const float* __restrict__ vals,
                                               int* __restrict__ gcur,
                                               int2* __restrict__ packed,
                                               int* __restrict__ ov_cnt,
                                               int4* __restrict__ ov) {
    __shared__ int hist[NBKT];
    __shared__ int off[NBKT];
    __shared__ int cur[NBKT];
    __shared__ int gbase[NBKT];
    __shared__ int wsum[16];
    __shared__ int stotal;
    __shared__ int2 stage[TILE];   // 32 KB
    __shared__ int dg[TILE];       // 16 KB
    const int tid = threadIdx.x;
    const int lane = tid & 63;
    const int wid = tid >> 6;      // 0..15
    const int e0 = blockIdx.x * TILE;

    for (int i = tid; i < NBKT; i += 1024) hist[i] = 0;
    __syncthreads();

    // pass 1: histogram; rows cached in registers (int4 vector load)
    const int eb = e0 + 4 * tid;
    int rr0 = -1, rr1 = -1, rr2 = -1, rr3 = -1;
    if (eb + 3 < N_EDGES) {
        int4 r4 = *(const int4*)(rows + eb);
        rr0 = r4.x; rr1 = r4.y; rr2 = r4.z; rr3 = r4.w;
    } else {
        if (eb + 0 < N_EDGES) rr0 = rows[eb + 0];
        if (eb + 1 < N_EDGES) rr1 = rows[eb + 1];
        if (eb + 2 < N_EDGES) rr2 = rows[eb + 2];
        if (eb + 3 < N_EDGES) rr3 = rows[eb + 3];
    }
    if (rr0 >= 0) atomicAdd(&hist[rr0 >> 7], 1);
    if (rr1 >= 0) atomicAdd(&hist[rr1 >> 7], 1);
    if (rr2 >= 0) atomicAdd(&hist[rr2 >> 7], 1);
    if (rr3 >= 0) atomicAdd(&hist[rr3 >> 7], 1);
    __syncthreads();

    // exclusive scan hist[0..NBKT): wave shfl scan + 16-partial combine
    // (NBKT=782 <= 1024; waves 13..15 contribute zero partials)
    int v = (tid < NBKT) ? hist[tid] : 0;
    int incl = v;
    for (int o = 1; o < 64; o <<= 1) {
        int t = __shfl_up(incl, o, 64);
        if (lane >= o) incl += t;
    }
    if (lane == 63) wsum[wid] = incl;
    __syncthreads();
    if (wid == 0 && lane < 16) {
        int s = wsum[lane];
        int si = s;
        for (int o = 1; o < 16; o <<= 1) {
            int t = __shfl_up(si, o, 64);
            if (lane >= o) si += t;
        }
        wsum[lane] = si - s;           // exclusive wave offset
        if (lane == 15) stotal = si;   // tile total
    }
    __syncthreads();
    int excl = incl - v + wsum[wid];
    if (tid < NBKT) { off[tid] = excl; cur[tid] = excl; }

    // bulk global reservation: one atomic per non-empty bucket
    for (int b = tid; b < NBKT; b += 1024) {
        int c = hist[b];
        gbase[b] = c ? atomicAdd(&gcur[b], c) : 0;
    }
    __syncthreads();

    // pass 2: grouped placement into LDS staging (cols/vals via int4/float4)
    int cc0 = 0, cc1 = 0, cc2 = 0, cc3 = 0;
    float vv0 = 0.f, vv1 = 0.f, vv2 = 0.f, vv3 = 0.f;
    if (eb + 3 < N_EDGES) {
        int4 c4 = *(const int4*)(cols + eb);
        float4 v4 = *(const float4*)(vals + eb);
        cc0 = c4.x; cc1 = c4.y; cc2 = c4.z; cc3 = c4.w;
        vv0 = v4.x; vv1 = v4.y; vv2 = v4.z; vv3 = v4.w;
    } else {
        if (eb + 0 < N_EDGES) { cc0 = cols[eb + 0]; vv0 = vals[eb + 0]; }
        if (eb + 1 < N_EDGES) { cc1 = cols[eb + 1]; vv1 = vals[eb + 1]; }
        if (eb + 2 < N_EDGES) { cc2 = cols[eb + 2]; vv2 = vals[eb + 2]; }
        if (eb + 3 < N_EDGES) { cc3 = cols[eb + 3]; vv3 = vals[eb + 3]; }
    }
#define PLACE(RR, CC, VV)                                                     \
    if (RR >= 0) {                                                            \
        int b_ = RR >> 7;                                                     \
        int p_ = atomicAdd(&cur[b_], 1);                                      \
        stage[p_] = make_int2(((RR & (RPB - 1)) << 17) | CC,                  \
                              __float_as_int(VV));                            \
        int d_ = gbase[b_] + (p_ - off[b_]);                                  \
        dg[p_] = (d_ < CAP) ? (b_ * CAP + d_) : (0x40000000 | b_);            \
    }
    PLACE(rr0, cc0, vv0)
    PLACE(rr1, cc1, vv1)
    PLACE(rr2, cc2, vv2)
    PLACE(rr3, cc3, vv3)
#undef PLACE
    __syncthreads();

    // flush: consecutive staged elements -> consecutive global slots (dense lines)
    int total = stotal;
    for (int j = tid; j < total; j += 1024) {
        int d = dg[j];
        int2 ev = stage[j];
        if (d & 0x40000000) {          // overflow backstop (statistically never)
            int b_ = d & 0xFFFF;
            int ovi = atomicAdd(ov_cnt, 1);
            if (ovi < OVCAP) {
                int r = b_ * RPB + (((unsigned)ev.x) >> 17);
                ov[ovi] = make_int4(r, ev.x & 0x1FFFF, ev.y, 0);
            }
        } else {
            packed[d] = ev;
        }
    }
}

// ---------- fused binB+gather: one block per bucket ----------
// RPB=128: grid 782 blocks -> steady-state 2 blocks/CU (thread cap) = 32
// waves/CU during the gather (r11 measured 48% occupancy at grid 391 = the
// latency-bound limiter). LDS ~21KB. Inline overflow sweep at the end.
__global__ __launch_bounds__(1024) void k_bg(const float* __restrict__ x,
                                             const int* __restrict__ gcur,
                                             const int2* __restrict__ packed,
                                             const int* __restrict__ ov_cnt,
                                             const int4* __restrict__ ov,
                                             float* __restrict__ out) {
    __shared__ int2 stage[CAP];    // 18 KB
    __shared__ int h[RPB];
    __shared__ int ofs[RPB];
    __shared__ int cur[RPB];
    __shared__ int wsum[2];
    const int b = blockIdx.x;
    const int tid = threadIdx.x;
    const int lane = tid & 63;
    const int wid = tid >> 6;      // 0..15
    int n = gcur[b];
    if (n > CAP) n = CAP;
    const int base = b * CAP;

    if (tid < RPB) h[tid] = 0;
    __syncthreads();

    // load edges into registers + histogram rows
    int2 ereg[EPT];
    int lr[EPT];
#pragma unroll
    for (int jj = 0; jj < EPT; ++jj) {
        int j = tid + jj * 1024;
        lr[jj] = -1;
        if (j < n) {
            int2 e = packed[base + j];
            ereg[jj] = e;
            int r = ((unsigned)e.x) >> 17;
            lr[jj] = r;
            atomicAdd(&h[r], 1);
        }
    }
    __syncthreads();

    // exclusive scan h[0..127] (waves 0..1)
    int hv = (tid < RPB) ? h[tid] : 0;
    int incl = hv;
    for (int o = 1; o < 64; o <<= 1) {
        int t = __shfl_up(incl, o, 64);
        if (lane >= o) incl += t;
    }
    if (tid < RPB && lane == 63) wsum[wid] = incl;
    __syncthreads();
    if (wid == 0 && lane < 2) {
        int s = wsum[lane];
        int si = s;
        {
            int t = __shfl_up(si, 1, 64);
            if (lane >= 1) si += t;
        }
        wsum[lane] = si - s;           // exclusive wave offset
    }
    __syncthreads();
    if (tid < RPB) {
        int o2 = incl - hv + wsum[wid];
        ofs[tid] = o2;
        cur[tid] = o2;
    }
    __syncthreads();

    // place row-sorted into LDS (source = registers -> no RAW hazard)
#pragma unroll
    for (int jj = 0; jj < EPT; ++jj) {
        if (lr[jj] >= 0) {
            int p = atomicAdd(&cur[lr[jj]], 1);
            stage[p] = ereg[jj];
        }
    }
    __syncthreads();

    // gather: wave wid handles rows wid*8 .. wid*8+7
    const int half = lane >> 5;    // 0: even edges, 1: odd edges
    const int hl = lane & 31;      // dim-pair index
    const float2* __restrict__ x2 = (const float2*)x;
    for (int i = 0; i < 8; ++i) {
        int r = wid * 8 + i;
        int grow = b * RPB + r;
        if (grow >= N_NODES) break;
        int deg = h[r];
        int beg = ofs[r];
        float ax = 0.f, ay = 0.f;
        for (int j0 = 0; j0 < deg; j0 += 16) {
            float pv[8];
            float2 xv[8];
#pragma unroll
            for (int k = 0; k < 8; ++k) {
                int j = j0 + 2 * k + half;
                int2 e = (j < deg) ? stage[beg + j] : make_int2(0, 0);
                pv[k] = __int_as_float(e.y);               // 0 for pad
                xv[k] = x2[(e.x & 0x1FFFF) * 32 + hl];     // x[0] row for pad
            }
#pragma unroll
            for (int k = 0; k < 8; ++k) {
                ax += pv[k] * xv[k].x;
                ay += pv[k] * xv[k].y;
            }
        }
        ax += __shfl_xor(ax, 32);
        ay += __shfl_xor(ay, 32);
        if (half == 0) {
            ((float2*)out)[(size_t)grow * 32 + hl] = make_float2(ax, ay);
        }
    }

    // inline overflow cleanup for this bucket's rows (expected nov==0)
    __syncthreads();   // drain gather stores before atomics on same rows
    int nov = *ov_cnt;
    if (nov > OVCAP) nov = OVCAP;
    for (int i = wid; i < nov; i += 16) {
        int4 e = ov[i];
        if ((e.x >> 7) == b) {
            atomicAdd(&out[(size_t)e.x * EMBED_DIM + lane],
                      __int_as_float(e.z) * x[(size_t)e.y * EMBED_DIM + lane]);
        }
    }
}

// ---------- fallback (ws too small): atomic scatter ----------
__global__ __launch_bounds__(256) void spmm_scatter_kernel(
    const float* __restrict__ x, const float* __restrict__ vals,
    const int* __restrict__ rows, const int* __restrict__ cols,
    float* __restrict__ out) {
    const int wave_in_block = threadIdx.x >> 6;
    const int lane = threadIdx.x & 63;
    const int e = blockIdx.x * 4 + wave_in_block;
    if (e >= N_EDGES) return;
    const float m = vals[e] * x[cols[e] * EMBED_DIM + lane];
    atomicAdd(&out[rows[e] * EMBED_DIM + lane], m);
}

extern "C" void kernel_launch(void* const* d_in, const int* in_sizes, int n_in,
                              void* d_out, int out_size, void* d_ws, size_t ws_size,
                              hipStream_t stream) {
    const float* x    = (const float*)d_in[0];
    const float* vals = (const float*)d_in[1];
    const int*   rows = (const int*)d_in[2];
    const int*   cols = (const int*)d_in[3];
    float* out = (float*)d_out;

    // ws layout: packed[NBKT*CAP] int2 | ov[OVCAP] int4 | gcur[NBKT] | ov_cnt
    const size_t packed_b = (size_t)NBKT * CAP * 8;         // 14,413,824 (16B-aligned)
    const size_t ov_b     = (size_t)OVCAP * 16;
    const size_t need = packed_b + ov_b + ((size_t)NBKT + 1) * 4;
    if (ws_size < need) {
        hipMemsetAsync(out, 0, (size_t)out_size * sizeof(float), stream);
        spmm_scatter_kernel<<<(N_EDGES + 3) / 4, 256, 0, stream>>>(x, vals, rows, cols, out);
        return;
    }

    int2* packed  = (int2*)d_ws;
    int4* ov      = (int4*)((char*)d_ws + packed_b);
    int*  gcur    = (int*)((char*)d_ws + packed_b + ov_b);
    int*  ov_cnt  = gcur + NBKT;

    // single memset: gcur[NBKT] + ov_cnt adjacent
    hipMemsetAsync(gcur, 0, ((size_t)NBKT + 1) * sizeof(int), stream);

    k_binA<<<NTILE, 1024, 0, stream>>>(rows, cols, vals, gcur, packed, ov_cnt, ov);
    k_bg<<<NBKT, 1024, 0, stream>>>(x, gcur, (const int2*)packed, ov_cnt, ov, out);
}